// Round 4
// baseline (364.633 us; speedup 1.0000x reference)
//
#include <hip/hip_runtime.h>
#include <math.h>

#define KK 256
#define NN 65536
#define WW 48            // scan lookback window; decay<=e^-1 -> tail ~e^-48
#define TS 128           // scan t-tile (512 blocks)
#define NTILE (NN / TS)  // 512
#define RT 65            // LDS row stride in uints (=130 bf16); odd -> conflict-free
#define TG 64            // gemm t-tile

typedef __bf16 bf16x8 __attribute__((ext_vector_type(8)));
typedef float f32x4 __attribute__((ext_vector_type(4)));

static __device__ __forceinline__ unsigned pack2(float a, float b) {
  union { __bf16 h; unsigned short u; } x, y;
  x.h = (__bf16)a; y.h = (__bf16)b;
  return (unsigned)x.u | ((unsigned)y.u << 16);
}
static __device__ __forceinline__ float lo16(unsigned u) {
  return __builtin_bit_cast(float, u << 16);
}
static __device__ __forceinline__ float hi16(unsigned u) {
  return __builtin_bit_cast(float, u & 0xffff0000u);
}

// ---------------------------------------------------------------------------
// Kernel 1 (scan): block c covers t in [c*TS, c*TS+TS).
//   Phase 1: coalesced float4 stage of obs[:, tile] -> LDS bf16 [k][RT uints].
//   Phase 2: thread k scans row k from LDS (2-way bank = free), writes
//   ST[t][k] bf16 (coalesced across k) + per-tile row sums.
// ---------------------------------------------------------------------------
__global__ __launch_bounds__(256, 2) void scan_kernel(const float* __restrict__ obs,
                                                      const float* __restrict__ Beta,
                                                      __bf16* __restrict__ ST,
                                                      float* __restrict__ partial) {
  __shared__ unsigned ob[KK][RT];  // 66.6 KB -> 2 blocks/CU
  const int tid = threadIdx.x;
  const int t0 = blockIdx.x * TS;

  {  // ---- phase 1: cooperative coalesced load ----
    const int tq = tid & 31;   // float4 index within row (32 x 4 = 128 t)
    const int kq = tid >> 5;   // row-within-octet
#pragma unroll 4
    for (int r = 0; r < 32; ++r) {
      const int k = r * 8 + kq;
      float4 v = *(const float4*)(obs + (size_t)k * NN + t0 + tq * 4);
      ob[k][2 * tq]     = pack2(v.x, v.y);
      ob[k][2 * tq + 1] = pack2(v.z, v.w);
    }
  }
  __syncthreads();

  // ---- phase 2: per-thread scan ----
  const int k = tid;
  const float beta = Beta[k];
  const float decay = __expf(-beta);
  const float* row = obs + (size_t)k * NN;
  float g = 0.f;  // ~ G[k, t0-WW]; tail < e^-48
  if (t0 > 0) {   // window preamble from global: 3 fully-used 64B lines/thread
    const float4* p = (const float4*)(row + t0 - WW);
#pragma unroll
    for (int i = 0; i < WW / 4; ++i) {
      float4 v = p[i];
      g = decay * (g + v.x); g = decay * (g + v.y);
      g = decay * (g + v.z); g = decay * (g + v.w);
    }
  }
  __bf16* st = ST + (size_t)t0 * KK + k;
  st[0] = (__bf16)(beta * g);  // S[t0] (t0==0 -> exactly 0)
  float rsum = 0.f;
#pragma unroll 8
  for (int i = 0; i < TS / 2 - 1; ++i) {
    unsigned u = ob[k][i];
    float o0 = lo16(u), o1 = hi16(u);
    rsum += o0 + o1;
    g = decay * (g + o0); st[(size_t)(2 * i + 1) * KK] = (__bf16)(beta * g);
    g = decay * (g + o1); st[(size_t)(2 * i + 2) * KK] = (__bf16)(beta * g);
  }
  {  // last pair: t=TS-2 feeds S[TS-1]; t=TS-1 only feeds rsum
    unsigned u = ob[k][TS / 2 - 1];
    float o0 = lo16(u), o1 = hi16(u);
    rsum += o0 + o1;
    g = decay * (g + o0); st[(size_t)(TS - 1) * KK] = (__bf16)(beta * g);
  }
  partial[blockIdx.x * KK + k] = rsum;  // coalesced
}

// ---------------------------------------------------------------------------
// Kernel 2 (prep): finalize mu0 from NTILE partials/row, Alpha -> bf16,
//   zero loglik accumulator. Block j handles row j.
// ---------------------------------------------------------------------------
__global__ __launch_bounds__(256) void prep_kernel(const float* __restrict__ Alpha,
                                                   const float* __restrict__ partial,
                                                   float* __restrict__ mu0,
                                                   __bf16* __restrict__ AlphaB,
                                                   float* __restrict__ out) {
  const int j = blockIdx.x;
  const int tid = threadIdx.x;
  AlphaB[(size_t)j * KK + tid] = (__bf16)Alpha[(size_t)j * KK + tid];
  float s = partial[(size_t)tid * KK + j] + partial[(size_t)(tid + 256) * KK + j];
  __shared__ float red[256];
  red[tid] = s;
  __syncthreads();
  for (int off = 128; off > 0; off >>= 1) {
    if (tid < off) red[tid] += red[tid + off];
    __syncthreads();
  }
  if (tid == 0) {
    mu0[j] = red[0] * (1.0f / NN) * 0.1f + 0.01f;
    if (j == 0) out[0] = 0.f;  // d_out is poisoned; zero the accumulator
  }
}

// ---------------------------------------------------------------------------
// Kernel 3 (gemm): no LDS, no barriers. 2048 blocks: b = tile*2 + jhalf.
//   Block covers t in [tile*TG, +TG), j in [jhalf*128, +128).
//   Wave w: jsel = w&1 (64 j), tsel = w>>1 (32 t). acc[4js][2ts].
//   8 blocks/CU -> 100% occupancy target.
// ---------------------------------------------------------------------------
__global__ __launch_bounds__(256, 8) void gemm_kernel(const float* __restrict__ obs,
                                                      const float* __restrict__ mu0,
                                                      const __bf16* __restrict__ AlphaB,
                                                      const __bf16* __restrict__ ST,
                                                      float* __restrict__ out) {
  const int tid = threadIdx.x;
  const int b = blockIdx.x;
  const int t0 = (b >> 1) * TG;
  const int jh = (b & 1) * 128;
  const int wave = tid >> 6;
  const int lane = tid & 63;
  const int lquad = lane >> 4;  // k-octet in frag / j-sub in C
  const int l16 = lane & 15;
  const int j0 = jh + (wave & 1) * 64;
  const int tt0 = t0 + (wave >> 1) * 32;

  f32x4 acc[4][2];  // [jsub][tsub]
#pragma unroll
  for (int a = 0; a < 4; ++a)
#pragma unroll
    for (int c = 0; c < 2; ++c) acc[a][c] = (f32x4){0.f, 0.f, 0.f, 0.f};

  const __bf16* Abase = AlphaB + (size_t)(j0 + l16) * KK + lquad * 8;
  const __bf16* Bbase = ST + (size_t)(tt0 + l16) * KK + lquad * 8;
#pragma unroll
  for (int k0 = 0; k0 < KK; k0 += 32) {
    bf16x8 afrag[4], bfrag[2];
#pragma unroll
    for (int js = 0; js < 4; ++js)
      afrag[js] = *(const bf16x8*)(Abase + (size_t)js * 16 * KK + k0);
#pragma unroll
    for (int ts = 0; ts < 2; ++ts)
      bfrag[ts] = *(const bf16x8*)(Bbase + (size_t)ts * 16 * KK + k0);
#pragma unroll
    for (int js = 0; js < 4; ++js)
#pragma unroll
      for (int ts = 0; ts < 2; ++ts)
        acc[js][ts] = __builtin_amdgcn_mfma_f32_16x16x32_bf16(
            afrag[js], bfrag[ts], acc[js][ts], 0, 0, 0);
  }

  // ---- epilogue: softplus, lams0/lams1, loglik partial ----
  float partial = 0.f;
  float* lams0 = out + 1;
  float* lams1 = out + 1 + (size_t)KK * NN;
#pragma unroll
  for (int js = 0; js < 4; ++js) {
#pragma unroll
    for (int r = 0; r < 4; ++r) {
      const int j = j0 + js * 16 + lquad * 4 + r;  // D-layout row
      const float m = mu0[j];
      const size_t rowoff = (size_t)j * NN + tt0 + l16;
#pragma unroll
      for (int ts = 0; ts < 2; ++ts) {
        float v = acc[js][ts][r];                    // v >= 0 always
        float lam = v + __logf(1.f + __expf(-v));    // stable softplus
        if (tt0 + ts * 16 + l16 == 0) lam = 0.f;     // lams1[:,0] = 0
        lams1[rowoff + ts * 16] = lam;
        lams0[rowoff + ts * 16] = m;
        const float o = obs[rowoff + ts * 16];
        partial += o * __logf(m + lam + 1e-5f) - m - lam;
      }
    }
  }

#pragma unroll
  for (int off = 32; off > 0; off >>= 1)
    partial += __shfl_down(partial, off, 64);
  if (lane == 0) atomicAdd(out, partial);
}

// ---------------------------------------------------------------------------
extern "C" void kernel_launch(void* const* d_in, const int* in_sizes, int n_in,
                              void* d_out, int out_size, void* d_ws, size_t ws_size,
                              hipStream_t stream) {
  const float* obs   = (const float*)d_in[0];
  const float* Beta  = (const float*)d_in[1];
  const float* Alpha = (const float*)d_in[2];
  float* out = (float*)d_out;

  float* partial = (float*)d_ws;            // NTILE*KK floats = 512 KB
  float* mu0 = partial + NTILE * KK;        // 1 KB
  __bf16* AlphaB = (__bf16*)(mu0 + 256);    // 128 KB
  __bf16* ST = AlphaB + KK * KK;            // KK*NN bf16 = 32 MB

  hipLaunchKernelGGL(scan_kernel, dim3(NTILE), dim3(256), 0, stream,
                     obs, Beta, ST, partial);
  hipLaunchKernelGGL(prep_kernel, dim3(KK), dim3(256), 0, stream,
                     Alpha, partial, mu0, AlphaB, out);
  hipLaunchKernelGGL(gemm_kernel, dim3(2 * NN / TG), dim3(256), 0, stream,
                     obs, mu0, AlphaB, ST, out);
}

// Round 5
// 363.264 us; speedup vs baseline: 1.0038x; 1.0038x over previous
//
#include <hip/hip_runtime.h>
#include <math.h>

#define KK 256
#define NN 65536
#define WW 48            // scan lookback window; decay<=e^-1 -> tail ~e^-48
#define TS 64            // scan t-tile (1024 blocks, 4/CU)
#define NTILE (NN / TS)  // 1024
#define RT 33            // LDS row stride in uints (=66 bf16); odd -> conflict-free
#define TG 32            // gemm t-tile (2048 blocks, 8/CU)

typedef __bf16 bf16x8 __attribute__((ext_vector_type(8)));
typedef float f32x4 __attribute__((ext_vector_type(4)));

static __device__ __forceinline__ unsigned pack2(float a, float b) {
  union { __bf16 h; unsigned short u; } x, y;
  x.h = (__bf16)a; y.h = (__bf16)b;
  return (unsigned)x.u | ((unsigned)y.u << 16);
}
static __device__ __forceinline__ float lo16(unsigned u) {
  return __builtin_bit_cast(float, u << 16);
}
static __device__ __forceinline__ float hi16(unsigned u) {
  return __builtin_bit_cast(float, u & 0xffff0000u);
}

// ---------------------------------------------------------------------------
// Kernel 1 (scan): block c covers t in [c*TS, c*TS+TS).
//   Phase 1: coalesced float4 stage of obs[:, tile] -> LDS bf16 [k][RT uints].
//   Phase 2: thread k: WW preamble from global (3 full 64B lines/lane, L1-
//   friendly), then 64-step scan from LDS; writes ST[t][k] bf16 (coalesced)
//   and per-tile row sums.
// ---------------------------------------------------------------------------
__global__ __launch_bounds__(256, 4) void scan_kernel(const float* __restrict__ obs,
                                                      const float* __restrict__ Beta,
                                                      __bf16* __restrict__ ST,
                                                      float* __restrict__ partial) {
  __shared__ unsigned ob[KK][RT];  // 33.8 KB -> 4 blocks/CU
  const int tid = threadIdx.x;
  const int t0 = blockIdx.x * TS;

  {  // ---- phase 1: cooperative coalesced load ----
    const int tq = tid & 15;   // float4 index within row (16 x 4 = 64 t)
    const int kq = tid >> 4;   // row-within-16-group
#pragma unroll 4
    for (int r = 0; r < 16; ++r) {
      const int k = r * 16 + kq;
      float4 v = *(const float4*)(obs + (size_t)k * NN + t0 + tq * 4);
      ob[k][2 * tq]     = pack2(v.x, v.y);
      ob[k][2 * tq + 1] = pack2(v.z, v.w);
    }
  }
  __syncthreads();

  // ---- phase 2: per-thread scan ----
  const int k = tid;
  const float beta = Beta[k];
  const float decay = __expf(-beta);
  const float* row = obs + (size_t)k * NN;
  float g = 0.f;  // ~ G[k, t0-WW]; tail < e^-48
  if (t0 > 0) {
    const float4* p = (const float4*)(row + t0 - WW);
#pragma unroll
    for (int i = 0; i < WW / 4; ++i) {
      float4 v = p[i];
      g = decay * (g + v.x); g = decay * (g + v.y);
      g = decay * (g + v.z); g = decay * (g + v.w);
    }
  }
  __bf16* st = ST + (size_t)t0 * KK + k;
  st[0] = (__bf16)(beta * g);  // S[t0] (t0==0 -> exactly 0)
  float rsum = 0.f;
#pragma unroll 8
  for (int i = 0; i < TS / 2 - 1; ++i) {
    unsigned u = ob[k][i];
    float o0 = lo16(u), o1 = hi16(u);
    rsum += o0 + o1;
    g = decay * (g + o0); st[(size_t)(2 * i + 1) * KK] = (__bf16)(beta * g);
    g = decay * (g + o1); st[(size_t)(2 * i + 2) * KK] = (__bf16)(beta * g);
  }
  {  // last pair: first elem feeds S[TS-1]; second only feeds rsum
    unsigned u = ob[k][TS / 2 - 1];
    float o0 = lo16(u), o1 = hi16(u);
    rsum += o0 + o1;
    g = decay * (g + o0); st[(size_t)(TS - 1) * KK] = (__bf16)(beta * g);
  }
  partial[blockIdx.x * KK + k] = rsum;  // coalesced
}

// ---------------------------------------------------------------------------
// Kernel 2 (prep): finalize mu0 from NTILE partials/row, Alpha -> bf16,
//   zero loglik accumulator. Block j handles row j.
// ---------------------------------------------------------------------------
__global__ __launch_bounds__(256) void prep_kernel(const float* __restrict__ Alpha,
                                                   const float* __restrict__ partial,
                                                   float* __restrict__ mu0,
                                                   __bf16* __restrict__ AlphaB,
                                                   float* __restrict__ out) {
  const int j = blockIdx.x;
  const int tid = threadIdx.x;
  AlphaB[(size_t)j * KK + tid] = (__bf16)Alpha[(size_t)j * KK + tid];
  float s = 0.f;
#pragma unroll
  for (int i = 0; i < NTILE / 256; ++i)
    s += partial[(size_t)(tid + 256 * i) * KK + j];
  __shared__ float red[256];
  red[tid] = s;
  __syncthreads();
  for (int off = 128; off > 0; off >>= 1) {
    if (tid < off) red[tid] += red[tid + off];
    __syncthreads();
  }
  if (tid == 0) {
    mu0[j] = red[0] * (1.0f / NN) * 0.1f + 0.01f;
    if (j == 0) out[0] = 0.f;  // d_out is poisoned; zero the accumulator
  }
}

// ---------------------------------------------------------------------------
// Kernel 3 (gemm): no LDS, no barriers. 2048 blocks, block b: t in
//   [b*TG, b*TG+TG), ALL 256 j (each ST byte read by exactly one block).
//   Wave w: j in [64w, 64w+64), all 32 t. MFMA 16x16x32 bf16, B-frags straight
//   from ST. Epilogue: softplus, lams0/lams1, loglik partial.
// ---------------------------------------------------------------------------
__global__ __launch_bounds__(256, 8) void gemm_kernel(const float* __restrict__ obs,
                                                      const float* __restrict__ mu0,
                                                      const __bf16* __restrict__ AlphaB,
                                                      const __bf16* __restrict__ ST,
                                                      float* __restrict__ out) {
  const int tid = threadIdx.x;
  const int t0 = blockIdx.x * TG;
  const int wave = tid >> 6;
  const int lane = tid & 63;
  const int lquad = lane >> 4;  // k-octet in frag / j-sub in C
  const int l16 = lane & 15;
  const int j0 = wave * 64;

  f32x4 acc[4][2];  // [jsub][tsub]
#pragma unroll
  for (int a = 0; a < 4; ++a)
#pragma unroll
    for (int c = 0; c < 2; ++c) acc[a][c] = (f32x4){0.f, 0.f, 0.f, 0.f};

  const __bf16* Abase = AlphaB + (size_t)(j0 + l16) * KK + lquad * 8;
  const __bf16* Bbase = ST + (size_t)(t0 + l16) * KK + lquad * 8;
#pragma unroll
  for (int k0 = 0; k0 < KK; k0 += 32) {
    bf16x8 afrag[4], bfrag[2];
#pragma unroll
    for (int js = 0; js < 4; ++js)
      afrag[js] = *(const bf16x8*)(Abase + (size_t)js * 16 * KK + k0);
#pragma unroll
    for (int ts = 0; ts < 2; ++ts)
      bfrag[ts] = *(const bf16x8*)(Bbase + (size_t)ts * 16 * KK + k0);
#pragma unroll
    for (int js = 0; js < 4; ++js)
#pragma unroll
      for (int ts = 0; ts < 2; ++ts)
        acc[js][ts] = __builtin_amdgcn_mfma_f32_16x16x32_bf16(
            afrag[js], bfrag[ts], acc[js][ts], 0, 0, 0);
  }

  // ---- epilogue: softplus, lams0/lams1, loglik partial ----
  float partial = 0.f;
  float* lams0 = out + 1;
  float* lams1 = out + 1 + (size_t)KK * NN;
#pragma unroll
  for (int js = 0; js < 4; ++js) {
#pragma unroll
    for (int r = 0; r < 4; ++r) {
      const int j = j0 + js * 16 + lquad * 4 + r;  // D-layout row
      const float m = mu0[j];
      const size_t rowoff = (size_t)j * NN + t0 + l16;
#pragma unroll
      for (int ts = 0; ts < 2; ++ts) {
        float v = acc[js][ts][r];                    // v >= 0 always
        float lam = v + __logf(1.f + __expf(-v));    // stable softplus
        if (t0 + ts * 16 + l16 == 0) lam = 0.f;      // lams1[:,0] = 0
        lams1[rowoff + ts * 16] = lam;
        lams0[rowoff + ts * 16] = m;
        const float o = obs[rowoff + ts * 16];
        partial += o * __logf(m + lam + 1e-5f) - m - lam;
      }
    }
  }

#pragma unroll
  for (int off = 32; off > 0; off >>= 1)
    partial += __shfl_down(partial, off, 64);
  if (lane == 0) atomicAdd(out, partial);
}

// ---------------------------------------------------------------------------
extern "C" void kernel_launch(void* const* d_in, const int* in_sizes, int n_in,
                              void* d_out, int out_size, void* d_ws, size_t ws_size,
                              hipStream_t stream) {
  const float* obs   = (const float*)d_in[0];
  const float* Beta  = (const float*)d_in[1];
  const float* Alpha = (const float*)d_in[2];
  float* out = (float*)d_out;

  float* partial = (float*)d_ws;            // NTILE*KK floats = 1 MB
  float* mu0 = partial + NTILE * KK;        // 1 KB
  __bf16* AlphaB = (__bf16*)(mu0 + 256);    // 128 KB
  __bf16* ST = AlphaB + KK * KK;            // KK*NN bf16 = 32 MB

  hipLaunchKernelGGL(scan_kernel, dim3(NTILE), dim3(256), 0, stream,
                     obs, Beta, ST, partial);
  hipLaunchKernelGGL(prep_kernel, dim3(KK), dim3(256), 0, stream,
                     Alpha, partial, mu0, AlphaB, out);
  hipLaunchKernelGGL(gemm_kernel, dim3(NN / TG), dim3(256), 0, stream,
                     obs, mu0, AlphaB, ST, out);
}